// Round 5
// baseline (396.769 us; speedup 1.0000x reference)
//
#include <hip/hip_runtime.h>

#define EPS_BN 1e-5f
#define PLANE4  65536u      // float4 per channel plane (512*512/4)
#define IMG40   655360u     // float4 per image (10 planes)
#define MSGF4   5242880u    // float4 offset of `message` inside d_out (8*10*PLANE4)

typedef unsigned int u32;
typedef __fp16 h2 __attribute__((ext_vector_type(2)));
typedef _Float16 v8h __attribute__((ext_vector_type(8)));
typedef float v4f __attribute__((ext_vector_type(4)));

union W32 { u32 u; float f; h2 h; };
union AB  { u32 u[4]; uint4 q; v8h h; };

__device__ __forceinline__ u32 packh(float a, float b){
  W32 w; w.h.x = (__fp16)a; w.h.y = (__fp16)b; return w.u;
}

#if __has_builtin(__builtin_amdgcn_cvt_pkrtz)
__device__ __forceinline__ u32 pku(float a, float b){
  W32 w; w.h = __builtin_amdgcn_cvt_pkrtz(a, b); return w.u;
}
#else
__device__ __forceinline__ u32 pku(float a, float b){ return packh(a, b); }
#endif

// Non-temporal store: outputs are write-once/never-read -> bypass LLC so the
// 251.6 MB input set can persist in the 256 MB Infinity Cache across
// graph-replay dispatches (FETCH_SIZE showed writes evicting ~half of it).
__device__ __forceinline__ void stnt(v4f* p, v4f v){
#if __has_builtin(__builtin_nontemporal_store)
  __builtin_nontemporal_store(v, p);
#else
  *p = v;
#endif
}

// ============================================================================
// ws layout (u32 words), per-lane MFMA fragments, BN-folded, f16:
//    0: F1a [64 lanes][4]  W1 tile0 (out rows 0-15),  sigma1 K-slots
//  256: F1b [64][4]        W1 tile1 (out rows 16-31)
//  512: F2  [64][4]        W2 (rows padded 10->16),   sigma2 K-slots
//  768: F3a [64][4]        W3 tile0,                  sigma3 K-slots
// 1024: F3b [64][4]        W3 tile1
// 1280: F4  [64][4]        W4 (rows padded 10->16),   sigma2 K-slots
// 1536: B1 [32] f32   1568: B2 [16]   1584: B3 [32]   1616: B4 [16]
// total 1632 words = 6528 B
//
// sigma1 (block1 conv1, concat(xh1,xh2) ch 0..19, K=32), lane group g=l>>4:
//   slot t0 = ch(g, 4+g); t1 = ch(8+g if g<2, 10+g); t2 = ch(14+g, 18+g if g<2); t3 = pad
// sigma2 (hidden 32ch): t0 = ch(4g,4g+1); t1 = (4g+2,4g+3); t2 = (16+4g,16+4g+1); t3 = (16+4g+2,+3)
//   -> exactly the lane's own D registers from conv1: ZERO cross-lane.
// sigma3 (block2 conv1, concat(xf ch0-9, msg ch10-19)):
//   g=0: t0=(10,11) t1=(12,13) t2=(0,1) t3=(2,3)
//   g=1: t0=(14,15) t1=(16,17) t2=(4,5) t3=(6,7)
//   g=2: t0=(18,19) t1=(8,9)   t2,t3 = pad ; g=3: all pad
//   -> msg channels stay in the lanes that computed them; xf planes = 4g+j.
//
// Pixel<->column binding: col c of an MFMA tile holds pixel quad c; fragment
// j = component j of each lane's float4 loads. 64 px/tile, 4 MFMA chains,
// float4 loads+stores (256 B contiguous per lane-group).
// ============================================================================

__device__ __forceinline__ float wv(const float* w, int ncol, int row, int k){
  return (k >= 0) ? w[row*ncol + k] : 0.f;
}

extern "C" __global__ void prep_kernel(
  const float* __restrict__ w1, const float* __restrict__ g1, const float* __restrict__ b1, const float* __restrict__ m1, const float* __restrict__ v1,
  const float* __restrict__ w2, const float* __restrict__ g2, const float* __restrict__ b2, const float* __restrict__ m2, const float* __restrict__ v2,
  const float* __restrict__ w3, const float* __restrict__ g3, const float* __restrict__ b3, const float* __restrict__ m3, const float* __restrict__ v3,
  const float* __restrict__ w4, const float* __restrict__ g4, const float* __restrict__ b4, const float* __restrict__ m4, const float* __restrict__ v4,
  u32* __restrict__ ws)
{
  const int t = threadIdx.x;

  // ---- F1a / F1b: W1 [32 out][20 ch], sigma1 ----
  for (int r = 0; r < 2; r++){
    for (int i = t; i < 256; i += 256){
      int lane = i >> 2, tq = i & 3, g = lane >> 4, m = (lane & 15) + 16*r;
      int ka, kb;
      if      (tq == 0){ ka = g;                      kb = 4 + g; }
      else if (tq == 1){ ka = (g < 2) ? 8 + g : -1;   kb = 10 + g; }
      else if (tq == 2){ ka = 14 + g;                 kb = (g < 2) ? 18 + g : -1; }
      else             { ka = -1;                     kb = -1; }
      float sc = g1[m] * rsqrtf(v1[m] + EPS_BN);
      ws[256*r + i] = packh(wv(w1, 20, m, ka) * sc, wv(w1, 20, m, kb) * sc);
    }
  }
  // ---- F2: W2 [10 out][32 ch] padded to 16 rows, sigma2 ----
  for (int i = t; i < 256; i += 256){
    int lane = i >> 2, tq = i & 3, g = lane >> 4, m = lane & 15;
    int k0 = (tq < 2) ? (4*g + 2*tq) : (16 + 4*g + 2*(tq - 2));
    u32 val = 0u;
    if (m < 10){
      float sc = g2[m] * rsqrtf(v2[m] + EPS_BN);
      val = packh(w2[m*32 + k0] * sc, w2[m*32 + k0 + 1] * sc);
    }
    ws[512 + i] = val;
  }
  // ---- F3a / F3b: W3 [32 out][20 ch], sigma3 ----
  for (int r = 0; r < 2; r++){
    for (int i = t; i < 256; i += 256){
      int lane = i >> 2, tq = i & 3, g = lane >> 4, m = (lane & 15) + 16*r;
      int ka = -1, kb = -1;
      if (g == 0){ const int base[4] = {10, 12, 0, 2}; ka = base[tq]; kb = ka + 1; }
      else if (g == 1){ const int base[4] = {14, 16, 4, 6}; ka = base[tq]; kb = ka + 1; }
      else if (g == 2){ if (tq == 0){ ka = 18; kb = 19; } else if (tq == 1){ ka = 8; kb = 9; } }
      float sc = g3[m] * rsqrtf(v3[m] + EPS_BN);
      ws[768 + 256*r + i] = packh(wv(w3, 20, m, ka) * sc, wv(w3, 20, m, kb) * sc);
    }
  }
  // ---- F4: W4 [10][32] padded, sigma2 ----
  for (int i = t; i < 256; i += 256){
    int lane = i >> 2, tq = i & 3, g = lane >> 4, m = lane & 15;
    int k0 = (tq < 2) ? (4*g + 2*tq) : (16 + 4*g + 2*(tq - 2));
    u32 val = 0u;
    if (m < 10){
      float sc = g4[m] * rsqrtf(v4[m] + EPS_BN);
      val = packh(w4[m*32 + k0] * sc, w4[m*32 + k0 + 1] * sc);
    }
    ws[1280 + i] = val;
  }
  // ---- biases (BN shift), zero-padded ----
  for (int i = t; i < 32; i += 256){
    float sc = g1[i] * rsqrtf(v1[i] + EPS_BN);
    W32 w; w.f = b1[i] - m1[i] * sc; ws[1536 + i] = w.u;
  }
  for (int i = t; i < 16; i += 256){
    W32 w; w.f = 0.f;
    if (i < 10){ float sc = g2[i] * rsqrtf(v2[i] + EPS_BN); w.f = b2[i] - m2[i] * sc; }
    ws[1568 + i] = w.u;
  }
  for (int i = t; i < 32; i += 256){
    float sc = g3[i] * rsqrtf(v3[i] + EPS_BN);
    W32 w; w.f = b3[i] - m3[i] * sc; ws[1584 + i] = w.u;
  }
  for (int i = t; i < 16; i += 256){
    W32 w; w.f = 0.f;
    if (i < 10){ float sc = g4[i] * rsqrtf(v4[i] + EPS_BN); w.f = b4[i] - m4[i] * sc; }
    ws[1616 + i] = w.u;
  }
}

__device__ __forceinline__ v4f mfma16(const AB& a, const AB& b, v4f c){
  return __builtin_amdgcn_mfma_f32_16x16x32_f16(a.h, b.h, c, 0, 0, 0);
}

__device__ __forceinline__ v4f relu4(v4f v){
  v.x = fmaxf(v.x, 0.f); v.y = fmaxf(v.y, 0.f);
  v.z = fmaxf(v.z, 0.f); v.w = fmaxf(v.w, 0.f);
  return v;
}

extern "C" __global__ __launch_bounds__(256) void fused_kernel(
  const v4f* __restrict__ xf, const v4f* __restrict__ xh1, const v4f* __restrict__ xh2,
  const u32* __restrict__ wsp, v4f* __restrict__ out)
{
  const unsigned tid  = threadIdx.x;
  const unsigned lane = tid & 63u;
  const unsigned c    = lane & 15u;     // pixel-quad column within tile
  const unsigned g    = lane >> 4;      // K-slot group / D-row group

  // ---- per-lane weight fragments + biases (persist in VGPRs) ----
  const uint4* W = (const uint4*)wsp;
  AB f1a, f1b, f2w, f3a, f3b, f4w;
  f1a.q = W[lane];        f1b.q = W[64 + lane];
  f2w.q = W[128 + lane];
  f3a.q = W[192 + lane];  f3b.q = W[256 + lane];
  f4w.q = W[320 + lane];
  const v4f* Bv = (const v4f*)(wsp + 1536);
  v4f c1a = Bv[g];      v4f c1b = Bv[4 + g];
  v4f c2  = Bv[8 + g];
  v4f c3a = Bv[12 + g]; v4f c3b = Bv[16 + g];
  v4f c4  = Bv[20 + g];

  // ---- static per-lane plane offsets (float4 units) ----
  const u32 po0 = g * PLANE4;
  const u32 po1 = (4u + g) * PLANE4;
  const u32 po2 = (8u + g) * PLANE4;          // valid g<2
  const u32 xo0 = (4u*g + 0u) * PLANE4;
  const u32 xo1 = (4u*g + 1u) * PLANE4;
  const u32 xo2 = (4u*g + 2u) * PLANE4;
  const u32 xo3 = (4u*g + 3u) * PLANE4;
  const bool v8  = (g < 2u);
  const bool vj0 = (4u*g + 0u < 10u), vj1 = (4u*g + 1u < 10u);
  const bool vj2 = (4u*g + 2u < 10u), vj3 = (4u*g + 3u < 10u);

  const unsigned wgl = blockIdx.x * 4u + (tid >> 6);  // global wave id
  const v4f z4 = {0.f, 0.f, 0.f, 0.f};

  for (int it = 0; it < 4; ++it){
    const unsigned tile = wgl * 4u + (unsigned)it;    // 64-pixel tile
    const unsigned q    = tile * 16u + c;             // global pixel-quad index
    const unsigned b    = q >> 16;                    // PLANE4 = 2^16
    const unsigned hw4  = q & (PLANE4 - 1u);
    const u32 base4 = b * IMG40 + hw4;

    // ---- loads: 256 B contiguous per lane-group per instruction ----
    v4f L0 = xh1[base4 + po0];
    v4f L1 = xh1[base4 + po1];
    v4f L2 = v8 ? xh1[base4 + po2] : z4;
    v4f M0 = xh2[base4 + po0];
    v4f M1 = xh2[base4 + po1];
    v4f M2 = v8 ? xh2[base4 + po2] : z4;
    v4f X0 = vj0 ? xf[base4 + xo0] : z4;
    v4f X1 = vj1 ? xf[base4 + xo1] : z4;
    v4f X2 = vj2 ? xf[base4 + xo2] : z4;
    v4f X3 = vj3 ? xf[base4 + xo3] : z4;

    // pack xf early (frees the raw float4s)
    u32 xt0[4], xt1[4];
    #pragma unroll
    for (int j = 0; j < 4; j++){ xt0[j] = pku(X0[j], X1[j]); xt1[j] = pku(X2[j], X3[j]); }

    // ---- block 1: conv1 + ReLU + conv2 + ReLU, per fragment j ----
    v4f dm[4];
    #pragma unroll
    for (int j = 0; j < 4; j++){
      AB b1u;
      b1u.u[0] = pku(L0[j], L1[j]);
      b1u.u[1] = pku(L2[j], M0[j]);
      b1u.u[2] = pku(M1[j], M2[j]);
      b1u.u[3] = 0u;
      v4f d0 = relu4(mfma16(f1a, b1u, c1a));
      v4f d1 = relu4(mfma16(f1b, b1u, c1b));
      AB hb;
      hb.u[0] = pku(d0.x, d0.y); hb.u[1] = pku(d0.z, d0.w);
      hb.u[2] = pku(d1.x, d1.y); hb.u[3] = pku(d1.z, d1.w);
      dm[j] = relu4(mfma16(f2w, hb, c2));
    }

    // ---- message stores: reassemble (j across components) -> dense nt dwordx4 ----
    if (vj0){ v4f r; r.x = dm[0].x; r.y = dm[1].x; r.z = dm[2].x; r.w = dm[3].x;
              stnt(&out[MSGF4 + base4 + xo0], r); }
    if (vj1){ v4f r; r.x = dm[0].y; r.y = dm[1].y; r.z = dm[2].y; r.w = dm[3].y;
              stnt(&out[MSGF4 + base4 + xo1], r); }
    if (vj2){ v4f r; r.x = dm[0].z; r.y = dm[1].z; r.z = dm[2].z; r.w = dm[3].z;
              stnt(&out[MSGF4 + base4 + xo2], r); }
    if (vj3){ v4f r; r.x = dm[0].w; r.y = dm[1].w; r.z = dm[2].w; r.w = dm[3].w;
              stnt(&out[MSGF4 + base4 + xo3], r); }

    // ---- block 2: conv1 + ReLU + conv2 + ReLU ----
    v4f dq[4];
    #pragma unroll
    for (int j = 0; j < 4; j++){
      u32 mt0 = pku(dm[j].x, dm[j].y), mt1 = pku(dm[j].z, dm[j].w);
      AB b3u;
      b3u.u[0] = mt0;
      b3u.u[1] = (g == 2u) ? xt0[j] : mt1;
      b3u.u[2] = xt0[j];
      b3u.u[3] = xt1[j];
      v4f e0 = relu4(mfma16(f3a, b3u, c3a));
      v4f e1 = relu4(mfma16(f3b, b3u, c3b));
      AB hb2;
      hb2.u[0] = pku(e0.x, e0.y); hb2.u[1] = pku(e0.z, e0.w);
      hb2.u[2] = pku(e1.x, e1.y); hb2.u[3] = pku(e1.z, e1.w);
      dq[j] = relu4(mfma16(f4w, hb2, c4));
    }

    if (vj0){ v4f r; r.x = dq[0].x; r.y = dq[1].x; r.z = dq[2].x; r.w = dq[3].x;
              stnt(&out[base4 + xo0], r); }
    if (vj1){ v4f r; r.x = dq[0].y; r.y = dq[1].y; r.z = dq[2].y; r.w = dq[3].y;
              stnt(&out[base4 + xo1], r); }
    if (vj2){ v4f r; r.x = dq[0].z; r.y = dq[1].z; r.z = dq[2].z; r.w = dq[3].z;
              stnt(&out[base4 + xo2], r); }
    if (vj3){ v4f r; r.x = dq[0].w; r.y = dq[1].w; r.z = dq[2].w; r.w = dq[3].w;
              stnt(&out[base4 + xo3], r); }
  }
}

extern "C" void kernel_launch(void* const* d_in, const int* in_sizes, int n_in,
                              void* d_out, int out_size, void* d_ws, size_t ws_size,
                              hipStream_t stream)
{
  u32* ws = (u32*)d_ws;
  prep_kernel<<<1, 256, 0, stream>>>(
    (const float*)d_in[3],  (const float*)d_in[4],  (const float*)d_in[5],  (const float*)d_in[6],  (const float*)d_in[7],
    (const float*)d_in[8],  (const float*)d_in[9],  (const float*)d_in[10], (const float*)d_in[11], (const float*)d_in[12],
    (const float*)d_in[13], (const float*)d_in[14], (const float*)d_in[15], (const float*)d_in[16], (const float*)d_in[17],
    (const float*)d_in[18], (const float*)d_in[19], (const float*)d_in[20], (const float*)d_in[21], (const float*)d_in[22],
    ws);

  // 2,097,152 px / 64 px per tile = 32768 tiles
  // = 2048 blocks x 4 waves x 4 tiles
  fused_kernel<<<2048, 256, 0, stream>>>(
    (const v4f*)d_in[0], (const v4f*)d_in[1], (const v4f*)d_in[2],
    ws, (v4f*)d_out);
}

// Round 6
// 382.959 us; speedup vs baseline: 1.0361x; 1.0361x over previous
//
#include <hip/hip_runtime.h>

#define EPS_BN 1e-5f
#define PLANE4  65536u      // float4 per channel plane (512*512/4)
#define IMG40   655360u     // float4 per image (10 planes)
#define MSGF4   5242880u    // float4 offset of `message` inside d_out (8*10*PLANE4)
#define NWAVES  8192u       // total waves in grid (2048 blocks x 4)

typedef unsigned int u32;
typedef __fp16 h2 __attribute__((ext_vector_type(2)));
typedef _Float16 v8h __attribute__((ext_vector_type(8)));
typedef float v4f __attribute__((ext_vector_type(4)));

union W32 { u32 u; float f; h2 h; };
union AB  { u32 u[4]; uint4 q; v8h h; };

__device__ __forceinline__ u32 packh(float a, float b){
  W32 w; w.h.x = (__fp16)a; w.h.y = (__fp16)b; return w.u;
}

#if __has_builtin(__builtin_amdgcn_cvt_pkrtz)
__device__ __forceinline__ u32 pku(float a, float b){
  W32 w; w.h = __builtin_amdgcn_cvt_pkrtz(a, b); return w.u;
}
#else
__device__ __forceinline__ u32 pku(float a, float b){ return packh(a, b); }
#endif

// ============================================================================
// ws layout (u32 words), per-lane MFMA fragments, BN-folded, f16:
//    0: F1a [64 lanes][4]  W1 tile0 (out rows 0-15),  sigma1 K-slots
//  256: F1b [64][4]        W1 tile1 (out rows 16-31)
//  512: F2  [64][4]        W2 (rows padded 10->16),   sigma2 K-slots
//  768: F3a [64][4]        W3 tile0,                  sigma3 K-slots
// 1024: F3b [64][4]        W3 tile1
// 1280: F4  [64][4]        W4 (rows padded 10->16),   sigma2 K-slots
// 1536: B1 [32] f32   1568: B2 [16]   1584: B3 [32]   1616: B4 [16]
// total 1632 words = 6528 B
//
// sigma1 (block1 conv1, concat(xh1,xh2) ch 0..19, K=32), lane group g=l>>4:
//   slot t0 = ch(g, 4+g); t1 = ch(8+g if g<2, 10+g); t2 = ch(14+g, 18+g if g<2); t3 = pad
// sigma2 (hidden 32ch): t0 = ch(4g,4g+1); t1 = (4g+2,4g+3); t2 = (16+4g,16+4g+1); t3 = (16+4g+2,+3)
//   -> exactly the lane's own D registers from conv1: ZERO cross-lane.
// sigma3 (block2 conv1, concat(xf ch0-9, msg ch10-19)):
//   g=0: t0=(10,11) t1=(12,13) t2=(0,1) t3=(2,3)
//   g=1: t0=(14,15) t1=(16,17) t2=(4,5) t3=(6,7)
//   g=2: t0=(18,19) t1=(8,9)   t2,t3 = pad ; g=3: all pad
//   -> msg channels stay in the lanes that computed them; xf planes = 4g+j.
//
// Pixel<->column binding: col c of an MFMA tile holds pixel quad c; fragment
// j = component j of each lane's float4 loads. 64 px/tile, 4 MFMA chains,
// float4 loads+stores (256 B contiguous per lane-group).
//
// Iteration order (NEW this round): GRID-STRIDE (tile = it*NWAVES + wave).
// At any instant the whole device reads/writes one contiguous ~2 MB sliding
// window per plane (copy-bench pattern) instead of 2048 scattered 4 KB
// fronts -- targets DRAM row/queue locality, the one untested variable.
// ============================================================================

__device__ __forceinline__ float wv(const float* w, int ncol, int row, int k){
  return (k >= 0) ? w[row*ncol + k] : 0.f;
}

extern "C" __global__ void prep_kernel(
  const float* __restrict__ w1, const float* __restrict__ g1, const float* __restrict__ b1, const float* __restrict__ m1, const float* __restrict__ v1,
  const float* __restrict__ w2, const float* __restrict__ g2, const float* __restrict__ b2, const float* __restrict__ m2, const float* __restrict__ v2,
  const float* __restrict__ w3, const float* __restrict__ g3, const float* __restrict__ b3, const float* __restrict__ m3, const float* __restrict__ v3,
  const float* __restrict__ w4, const float* __restrict__ g4, const float* __restrict__ b4, const float* __restrict__ m4, const float* __restrict__ v4,
  u32* __restrict__ ws)
{
  const int t = threadIdx.x;

  // ---- F1a / F1b: W1 [32 out][20 ch], sigma1 ----
  for (int r = 0; r < 2; r++){
    for (int i = t; i < 256; i += 256){
      int lane = i >> 2, tq = i & 3, g = lane >> 4, m = (lane & 15) + 16*r;
      int ka, kb;
      if      (tq == 0){ ka = g;                      kb = 4 + g; }
      else if (tq == 1){ ka = (g < 2) ? 8 + g : -1;   kb = 10 + g; }
      else if (tq == 2){ ka = 14 + g;                 kb = (g < 2) ? 18 + g : -1; }
      else             { ka = -1;                     kb = -1; }
      float sc = g1[m] * rsqrtf(v1[m] + EPS_BN);
      ws[256*r + i] = packh(wv(w1, 20, m, ka) * sc, wv(w1, 20, m, kb) * sc);
    }
  }
  // ---- F2: W2 [10 out][32 ch] padded to 16 rows, sigma2 ----
  for (int i = t; i < 256; i += 256){
    int lane = i >> 2, tq = i & 3, g = lane >> 4, m = lane & 15;
    int k0 = (tq < 2) ? (4*g + 2*tq) : (16 + 4*g + 2*(tq - 2));
    u32 val = 0u;
    if (m < 10){
      float sc = g2[m] * rsqrtf(v2[m] + EPS_BN);
      val = packh(w2[m*32 + k0] * sc, w2[m*32 + k0 + 1] * sc);
    }
    ws[512 + i] = val;
  }
  // ---- F3a / F3b: W3 [32 out][20 ch], sigma3 ----
  for (int r = 0; r < 2; r++){
    for (int i = t; i < 256; i += 256){
      int lane = i >> 2, tq = i & 3, g = lane >> 4, m = (lane & 15) + 16*r;
      int ka = -1, kb = -1;
      if (g == 0){ const int base[4] = {10, 12, 0, 2}; ka = base[tq]; kb = ka + 1; }
      else if (g == 1){ const int base[4] = {14, 16, 4, 6}; ka = base[tq]; kb = ka + 1; }
      else if (g == 2){ if (tq == 0){ ka = 18; kb = 19; } else if (tq == 1){ ka = 8; kb = 9; } }
      float sc = g3[m] * rsqrtf(v3[m] + EPS_BN);
      ws[768 + 256*r + i] = packh(wv(w3, 20, m, ka) * sc, wv(w3, 20, m, kb) * sc);
    }
  }
  // ---- F4: W4 [10][32] padded, sigma2 ----
  for (int i = t; i < 256; i += 256){
    int lane = i >> 2, tq = i & 3, g = lane >> 4, m = lane & 15;
    int k0 = (tq < 2) ? (4*g + 2*tq) : (16 + 4*g + 2*(tq - 2));
    u32 val = 0u;
    if (m < 10){
      float sc = g4[m] * rsqrtf(v4[m] + EPS_BN);
      val = packh(w4[m*32 + k0] * sc, w4[m*32 + k0 + 1] * sc);
    }
    ws[1280 + i] = val;
  }
  // ---- biases (BN shift), zero-padded ----
  for (int i = t; i < 32; i += 256){
    float sc = g1[i] * rsqrtf(v1[i] + EPS_BN);
    W32 w; w.f = b1[i] - m1[i] * sc; ws[1536 + i] = w.u;
  }
  for (int i = t; i < 16; i += 256){
    W32 w; w.f = 0.f;
    if (i < 10){ float sc = g2[i] * rsqrtf(v2[i] + EPS_BN); w.f = b2[i] - m2[i] * sc; }
    ws[1568 + i] = w.u;
  }
  for (int i = t; i < 32; i += 256){
    float sc = g3[i] * rsqrtf(v3[i] + EPS_BN);
    W32 w; w.f = b3[i] - m3[i] * sc; ws[1584 + i] = w.u;
  }
  for (int i = t; i < 16; i += 256){
    W32 w; w.f = 0.f;
    if (i < 10){ float sc = g4[i] * rsqrtf(v4[i] + EPS_BN); w.f = b4[i] - m4[i] * sc; }
    ws[1616 + i] = w.u;
  }
}

__device__ __forceinline__ v4f mfma16(const AB& a, const AB& b, v4f c){
  return __builtin_amdgcn_mfma_f32_16x16x32_f16(a.h, b.h, c, 0, 0, 0);
}

__device__ __forceinline__ v4f relu4(v4f v){
  v.x = fmaxf(v.x, 0.f); v.y = fmaxf(v.y, 0.f);
  v.z = fmaxf(v.z, 0.f); v.w = fmaxf(v.w, 0.f);
  return v;
}

extern "C" __global__ __launch_bounds__(256) void fused_kernel(
  const v4f* __restrict__ xf, const v4f* __restrict__ xh1, const v4f* __restrict__ xh2,
  const u32* __restrict__ wsp, v4f* __restrict__ out)
{
  const unsigned tid  = threadIdx.x;
  const unsigned lane = tid & 63u;
  const unsigned c    = lane & 15u;     // pixel-quad column within tile
  const unsigned g    = lane >> 4;      // K-slot group / D-row group

  // ---- per-lane weight fragments + biases (persist in VGPRs) ----
  const uint4* W = (const uint4*)wsp;
  AB f1a, f1b, f2w, f3a, f3b, f4w;
  f1a.q = W[lane];        f1b.q = W[64 + lane];
  f2w.q = W[128 + lane];
  f3a.q = W[192 + lane];  f3b.q = W[256 + lane];
  f4w.q = W[320 + lane];
  const v4f* Bv = (const v4f*)(wsp + 1536);
  v4f c1a = Bv[g];      v4f c1b = Bv[4 + g];
  v4f c2  = Bv[8 + g];
  v4f c3a = Bv[12 + g]; v4f c3b = Bv[16 + g];
  v4f c4  = Bv[20 + g];

  // ---- static per-lane plane offsets (float4 units) ----
  const u32 po0 = g * PLANE4;
  const u32 po1 = (4u + g) * PLANE4;
  const u32 po2 = (8u + g) * PLANE4;          // valid g<2
  const u32 xo0 = (4u*g + 0u) * PLANE4;
  const u32 xo1 = (4u*g + 1u) * PLANE4;
  const u32 xo2 = (4u*g + 2u) * PLANE4;
  const u32 xo3 = (4u*g + 3u) * PLANE4;
  const bool v8  = (g < 2u);
  const bool vj0 = (4u*g + 0u < 10u), vj1 = (4u*g + 1u < 10u);
  const bool vj2 = (4u*g + 2u < 10u), vj3 = (4u*g + 3u < 10u);

  const unsigned wgl = blockIdx.x * 4u + (tid >> 6);  // global wave id
  const v4f z4 = {0.f, 0.f, 0.f, 0.f};

  for (int it = 0; it < 4; ++it){
    // grid-stride tile order: device-wide contiguous sliding window
    const unsigned tile = (unsigned)it * NWAVES + wgl; // 64-pixel tile
    const unsigned q    = tile * 16u + c;              // global pixel-quad index
    const unsigned b    = q >> 16;                     // PLANE4 = 2^16
    const unsigned hw4  = q & (PLANE4 - 1u);
    const u32 base4 = b * IMG40 + hw4;

    // ---- loads: 256 B contiguous per lane-group per instruction ----
    v4f L0 = xh1[base4 + po0];
    v4f L1 = xh1[base4 + po1];
    v4f L2 = v8 ? xh1[base4 + po2] : z4;
    v4f M0 = xh2[base4 + po0];
    v4f M1 = xh2[base4 + po1];
    v4f M2 = v8 ? xh2[base4 + po2] : z4;
    v4f X0 = vj0 ? xf[base4 + xo0] : z4;
    v4f X1 = vj1 ? xf[base4 + xo1] : z4;
    v4f X2 = vj2 ? xf[base4 + xo2] : z4;
    v4f X3 = vj3 ? xf[base4 + xo3] : z4;

    // pack xf early (frees the raw float4s)
    u32 xt0[4], xt1[4];
    #pragma unroll
    for (int j = 0; j < 4; j++){ xt0[j] = pku(X0[j], X1[j]); xt1[j] = pku(X2[j], X3[j]); }

    // ---- block 1: conv1 + ReLU + conv2 + ReLU, per fragment j ----
    v4f dm[4];
    #pragma unroll
    for (int j = 0; j < 4; j++){
      AB b1u;
      b1u.u[0] = pku(L0[j], L1[j]);
      b1u.u[1] = pku(L2[j], M0[j]);
      b1u.u[2] = pku(M1[j], M2[j]);
      b1u.u[3] = 0u;
      v4f d0 = relu4(mfma16(f1a, b1u, c1a));
      v4f d1 = relu4(mfma16(f1b, b1u, c1b));
      AB hb;
      hb.u[0] = pku(d0.x, d0.y); hb.u[1] = pku(d0.z, d0.w);
      hb.u[2] = pku(d1.x, d1.y); hb.u[3] = pku(d1.z, d1.w);
      dm[j] = relu4(mfma16(f2w, hb, c2));
    }

    // ---- message stores: reassemble (j across components) -> dense dwordx4 ----
    if (vj0){ v4f r; r.x = dm[0].x; r.y = dm[1].x; r.z = dm[2].x; r.w = dm[3].x;
              out[MSGF4 + base4 + xo0] = r; }
    if (vj1){ v4f r; r.x = dm[0].y; r.y = dm[1].y; r.z = dm[2].y; r.w = dm[3].y;
              out[MSGF4 + base4 + xo1] = r; }
    if (vj2){ v4f r; r.x = dm[0].z; r.y = dm[1].z; r.z = dm[2].z; r.w = dm[3].z;
              out[MSGF4 + base4 + xo2] = r; }
    if (vj3){ v4f r; r.x = dm[0].w; r.y = dm[1].w; r.z = dm[2].w; r.w = dm[3].w;
              out[MSGF4 + base4 + xo3] = r; }

    // ---- block 2: conv1 + ReLU + conv2 + ReLU ----
    v4f dq[4];
    #pragma unroll
    for (int j = 0; j < 4; j++){
      u32 mt0 = pku(dm[j].x, dm[j].y), mt1 = pku(dm[j].z, dm[j].w);
      AB b3u;
      b3u.u[0] = mt0;
      b3u.u[1] = (g == 2u) ? xt0[j] : mt1;
      b3u.u[2] = xt0[j];
      b3u.u[3] = xt1[j];
      v4f e0 = relu4(mfma16(f3a, b3u, c3a));
      v4f e1 = relu4(mfma16(f3b, b3u, c3b));
      AB hb2;
      hb2.u[0] = pku(e0.x, e0.y); hb2.u[1] = pku(e0.z, e0.w);
      hb2.u[2] = pku(e1.x, e1.y); hb2.u[3] = pku(e1.z, e1.w);
      dq[j] = relu4(mfma16(f4w, hb2, c4));
    }

    if (vj0){ v4f r; r.x = dq[0].x; r.y = dq[1].x; r.z = dq[2].x; r.w = dq[3].x;
              out[base4 + xo0] = r; }
    if (vj1){ v4f r; r.x = dq[0].y; r.y = dq[1].y; r.z = dq[2].y; r.w = dq[3].y;
              out[base4 + xo1] = r; }
    if (vj2){ v4f r; r.x = dq[0].z; r.y = dq[1].z; r.z = dq[2].z; r.w = dq[3].z;
              out[base4 + xo2] = r; }
    if (vj3){ v4f r; r.x = dq[0].w; r.y = dq[1].w; r.z = dq[2].w; r.w = dq[3].w;
              out[base4 + xo3] = r; }
  }
}

extern "C" void kernel_launch(void* const* d_in, const int* in_sizes, int n_in,
                              void* d_out, int out_size, void* d_ws, size_t ws_size,
                              hipStream_t stream)
{
  u32* ws = (u32*)d_ws;
  prep_kernel<<<1, 256, 0, stream>>>(
    (const float*)d_in[3],  (const float*)d_in[4],  (const float*)d_in[5],  (const float*)d_in[6],  (const float*)d_in[7],
    (const float*)d_in[8],  (const float*)d_in[9],  (const float*)d_in[10], (const float*)d_in[11], (const float*)d_in[12],
    (const float*)d_in[13], (const float*)d_in[14], (const float*)d_in[15], (const float*)d_in[16], (const float*)d_in[17],
    (const float*)d_in[18], (const float*)d_in[19], (const float*)d_in[20], (const float*)d_in[21], (const float*)d_in[22],
    ws);

  // 2,097,152 px / 64 px per tile = 32768 tiles = 4 grid-stride sweeps of 8192 waves
  fused_kernel<<<2048, 256, 0, stream>>>(
    (const v4f*)d_in[0], (const v4f*)d_in[1], (const v4f*)d_in[2],
    ws, (v4f*)d_out);
}